// Round 1
// baseline (3507.887 us; speedup 1.0000x reference)
//
#include <hip/hip_runtime.h>
#include <hip/hip_bf16.h>
#include <math.h>

#define N_NODES 100000
#define N_EDGES 1600000
#define F_IN 165
#define C1 64          // H1*D1
#define NEG 0.2f

// ---------------- K1: h1 = x @ W1  (100000x165 @ 165x64) ----------------
// 256 threads, 64-row x 64-col tile, 4x4 register tile per thread.
__global__ __launch_bounds__(256) void k_gemm1(const float* __restrict__ x,
                                               const float* __restrict__ W1,
                                               float* __restrict__ h1) {
    __shared__ float Wl[192 * C1];   // k padded 165->192, zero-filled
    __shared__ float xs[64 * 33];    // 64 rows x 32 k, +1 pad to break bank conflicts
    const int t = threadIdx.x;
    for (int i = t; i < 192 * C1; i += 256) Wl[i] = (i < F_IN * C1) ? W1[i] : 0.f;

    const int base = blockIdx.x * 64;
    const int tr = t >> 4, tc = t & 15;
    float acc[4][4] = {};
    for (int k0 = 0; k0 < F_IN; k0 += 32) {
        __syncthreads();
        for (int i = t; i < 64 * 32; i += 256) {
            int r = i >> 5, kk = i & 31;
            int row = base + r, k = k0 + kk;
            xs[r * 33 + kk] = (row < N_NODES && k < F_IN) ? x[row * F_IN + k] : 0.f;
        }
        __syncthreads();
        #pragma unroll 8
        for (int kk = 0; kk < 32; ++kk) {
            float wv[4];
            #pragma unroll
            for (int j = 0; j < 4; ++j) wv[j] = Wl[(k0 + kk) * C1 + tc + 16 * j];
            #pragma unroll
            for (int i = 0; i < 4; ++i) {
                float xv = xs[(tr * 4 + i) * 33 + kk];
                #pragma unroll
                for (int j = 0; j < 4; ++j) acc[i][j] += xv * wv[j];
            }
        }
    }
    #pragma unroll
    for (int i = 0; i < 4; ++i) {
        int row = base + tr * 4 + i;
        if (row < N_NODES) {
            #pragma unroll
            for (int j = 0; j < 4; ++j) h1[row * C1 + tc + 16 * j] = acc[i][j];
        }
    }
}

// ---------------- K1b: alpha_s1/alpha_d1 = einsum(h1, a) ----------------
__global__ __launch_bounds__(256) void k_alpha1(const float* __restrict__ h1,
                                                const float* __restrict__ a_src,
                                                const float* __restrict__ a_dst,
                                                float* __restrict__ as1,
                                                float* __restrict__ ad1) {
    int t = threadIdx.x;
    int node = blockIdx.x * 4 + (t >> 6);
    int lane = t & 63;
    if (node >= N_NODES) return;
    float v = h1[node * 64 + lane];
    float s = v * a_src[lane];
    float d = v * a_dst[lane];
    s += __shfl_xor(s, 1); s += __shfl_xor(s, 2); s += __shfl_xor(s, 4);
    d += __shfl_xor(d, 1); d += __shfl_xor(d, 2); d += __shfl_xor(d, 4);
    if ((lane & 7) == 0) {
        as1[node * 8 + (lane >> 3)] = s;
        ad1[node * 8 + (lane >> 3)] = d;
    }
}

// ---------------- K2: edge pass layer 1 (8 threads per edge, one per head) ----------------
__global__ __launch_bounds__(256) void k_edge1(const int* __restrict__ ei,
                                               const float* __restrict__ h1,
                                               const float* __restrict__ as1,
                                               const float* __restrict__ ad1,
                                               float* __restrict__ z1,
                                               float* __restrict__ acc1) {
    int idx = blockIdx.x * 256 + threadIdx.x;
    int e = idx >> 3;
    int h = idx & 7;
    if (e >= N_EDGES + N_NODES) return;
    int s, d;
    if (e < N_EDGES) { s = ei[e]; d = ei[N_EDGES + e]; }
    else { s = e - N_EDGES; d = s; }
    float ev = as1[s * 8 + h] + ad1[d * 8 + h];
    ev = ev > 0.f ? ev : NEG * ev;
    float w = __expf(ev);
    atomicAdd(&z1[d * 8 + h], w);
    const float4* hp = (const float4*)(h1 + s * 64 + h * 8);
    float4 v0 = hp[0], v1 = hp[1];
    float* ap = acc1 + d * 64 + h * 8;
    atomicAdd(ap + 0, w * v0.x); atomicAdd(ap + 1, w * v0.y);
    atomicAdd(ap + 2, w * v0.z); atomicAdd(ap + 3, w * v0.w);
    atomicAdd(ap + 4, w * v1.x); atomicAdd(ap + 5, w * v1.y);
    atomicAdd(ap + 6, w * v1.z); atomicAdd(ap + 7, w * v1.w);
}

// ---------------- K3: out1 = elu(acc/z + b1); h2 = out1@W2; alpha2 ----------------
__global__ __launch_bounds__(256) void k_node1(const float* __restrict__ acc1,
                                               const float* __restrict__ z1,
                                               const float* __restrict__ b1,
                                               const float* __restrict__ W2,
                                               const float* __restrict__ a_src2,
                                               const float* __restrict__ a_dst2,
                                               float* __restrict__ h2,
                                               float* __restrict__ as2,
                                               float* __restrict__ ad2) {
    int t = threadIdx.x;
    int node = blockIdx.x * 4 + (t >> 6);
    int lane = t & 63;
    if (node >= N_NODES) return;
    float o = acc1[node * 64 + lane] / z1[node * 8 + (lane >> 3)] + b1[lane];
    o = o > 0.f ? o : expm1f(o);
    float p0 = o * W2[lane * 2 + 0];
    float p1 = o * W2[lane * 2 + 1];
    #pragma unroll
    for (int m = 1; m < 64; m <<= 1) { p0 += __shfl_xor(p0, m); p1 += __shfl_xor(p1, m); }
    if (lane == 0) {
        h2[node * 2 + 0] = p0;
        h2[node * 2 + 1] = p1;
        as2[node] = p0 * a_src2[0] + p1 * a_src2[1];
        ad2[node] = p0 * a_dst2[0] + p1 * a_dst2[1];
    }
}

// ---------------- K4: edge pass layer 2 (1 head, D=2) ----------------
__global__ __launch_bounds__(256) void k_edge2(const int* __restrict__ ei,
                                               const float* __restrict__ h2,
                                               const float* __restrict__ as2,
                                               const float* __restrict__ ad2,
                                               float* __restrict__ z2,
                                               float* __restrict__ acc2) {
    int e = blockIdx.x * 256 + threadIdx.x;
    if (e >= N_EDGES + N_NODES) return;
    int s, d;
    if (e < N_EDGES) { s = ei[e]; d = ei[N_EDGES + e]; }
    else { s = e - N_EDGES; d = s; }
    float ev = as2[s] + ad2[d];
    ev = ev > 0.f ? ev : NEG * ev;
    float w = __expf(ev);
    atomicAdd(&z2[d], w);
    atomicAdd(&acc2[d * 2 + 0], w * h2[s * 2 + 0]);
    atomicAdd(&acc2[d * 2 + 1], w * h2[s * 2 + 1]);
}

// ---------------- K5: final: /z + b2, log_softmax ----------------
__global__ __launch_bounds__(256) void k_final(const float* __restrict__ acc2,
                                               const float* __restrict__ z2,
                                               const float* __restrict__ b2,
                                               float* __restrict__ out) {
    int n = blockIdx.x * 256 + threadIdx.x;
    if (n >= N_NODES) return;
    float z = z2[n];
    float v0 = acc2[n * 2 + 0] / z + b2[0];
    float v1 = acc2[n * 2 + 1] / z + b2[1];
    float m = fmaxf(v0, v1);
    float lse = m + logf(__expf(v0 - m) + __expf(v1 - m));
    out[n * 2 + 0] = v0 - lse;
    out[n * 2 + 1] = v1 - lse;
}

extern "C" void kernel_launch(void* const* d_in, const int* in_sizes, int n_in,
                              void* d_out, int out_size, void* d_ws, size_t ws_size,
                              hipStream_t stream) {
    const float* x      = (const float*)d_in[0];
    const int*   ei     = (const int*)d_in[1];
    const float* W1     = (const float*)d_in[2];
    const float* a_src1 = (const float*)d_in[3];
    const float* a_dst1 = (const float*)d_in[4];
    const float* b1     = (const float*)d_in[5];
    const float* W2     = (const float*)d_in[6];
    const float* a_src2 = (const float*)d_in[7];
    const float* a_dst2 = (const float*)d_in[8];
    const float* b2     = (const float*)d_in[9];
    float* out = (float*)d_out;

    float* p = (float*)d_ws;
    float* h1   = p; p += N_NODES * 64;
    float* as1  = p; p += N_NODES * 8;
    float* ad1  = p; p += N_NODES * 8;
    float* z1   = p; p += N_NODES * 8;
    float* acc1 = p; p += N_NODES * 64;
    float* h2   = p; p += N_NODES * 2;
    float* as2  = p; p += N_NODES;
    float* ad2  = p; p += N_NODES;
    float* z2   = p; p += N_NODES;
    float* acc2 = p; p += N_NODES * 2;

    hipMemsetAsync(z1,   0, N_NODES * 8  * sizeof(float), stream);
    hipMemsetAsync(acc1, 0, N_NODES * 64 * sizeof(float), stream);
    hipMemsetAsync(z2,   0, N_NODES      * sizeof(float), stream);
    hipMemsetAsync(acc2, 0, N_NODES * 2  * sizeof(float), stream);

    k_gemm1<<<(N_NODES + 63) / 64, 256, 0, stream>>>(x, W1, h1);
    k_alpha1<<<(N_NODES + 3) / 4, 256, 0, stream>>>(h1, a_src1, a_dst1, as1, ad1);
    k_edge1<<<((N_EDGES + N_NODES) * 8 + 255) / 256, 256, 0, stream>>>(ei, h1, as1, ad1, z1, acc1);
    k_node1<<<(N_NODES + 3) / 4, 256, 0, stream>>>(acc1, z1, b1, W2, a_src2, a_dst2, h2, as2, ad2);
    k_edge2<<<(N_EDGES + N_NODES + 255) / 256, 256, 0, stream>>>(ei, h2, as2, ad2, z2, acc2);
    k_final<<<(N_NODES + 255) / 256, 256, 0, stream>>>(acc2, z2, b2, out);
}

// Round 2
// 538.705 us; speedup vs baseline: 6.5117x; 6.5117x over previous
//
#include <hip/hip_runtime.h>
#include <hip/hip_bf16.h>
#include <math.h>

#define N_NODES 100000
#define N_EDGES 1600000
#define F_IN 165
#define C1 64          // H1*D1
#define NEG 0.2f
#define NB 98          // ceil(N_NODES / 1024) scan blocks

// ---------------- K1: h1 = x @ W1  (100000x165 @ 165x64) ----------------
__global__ __launch_bounds__(256) void k_gemm1(const float* __restrict__ x,
                                               const float* __restrict__ W1,
                                               float* __restrict__ h1) {
    __shared__ float Wl[192 * C1];   // k padded 165->192, zero-filled
    __shared__ float xs[64 * 33];
    const int t = threadIdx.x;
    for (int i = t; i < 192 * C1; i += 256) Wl[i] = (i < F_IN * C1) ? W1[i] : 0.f;

    const int base = blockIdx.x * 64;
    const int tr = t >> 4, tc = t & 15;
    float acc[4][4] = {};
    for (int k0 = 0; k0 < F_IN; k0 += 32) {
        __syncthreads();
        for (int i = t; i < 64 * 32; i += 256) {
            int r = i >> 5, kk = i & 31;
            int row = base + r, k = k0 + kk;
            xs[r * 33 + kk] = (row < N_NODES && k < F_IN) ? x[row * F_IN + k] : 0.f;
        }
        __syncthreads();
        #pragma unroll 8
        for (int kk = 0; kk < 32; ++kk) {
            float wv[4];
            #pragma unroll
            for (int j = 0; j < 4; ++j) wv[j] = Wl[(k0 + kk) * C1 + tc + 16 * j];
            #pragma unroll
            for (int i = 0; i < 4; ++i) {
                float xv = xs[(tr * 4 + i) * 33 + kk];
                #pragma unroll
                for (int j = 0; j < 4; ++j) acc[i][j] += xv * wv[j];
            }
        }
    }
    #pragma unroll
    for (int i = 0; i < 4; ++i) {
        int row = base + tr * 4 + i;
        if (row < N_NODES) {
            #pragma unroll
            for (int j = 0; j < 4; ++j) h1[row * C1 + tc + 16 * j] = acc[i][j];
        }
    }
}

// ---------------- alpha_s1/alpha_d1 = einsum(h1, a) ----------------
__global__ __launch_bounds__(256) void k_alpha1(const float* __restrict__ h1,
                                                const float* __restrict__ a_src,
                                                const float* __restrict__ a_dst,
                                                float* __restrict__ as1,
                                                float* __restrict__ ad1) {
    int t = threadIdx.x;
    int node = blockIdx.x * 4 + (t >> 6);
    int lane = t & 63;
    if (node >= N_NODES) return;
    float v = h1[node * 64 + lane];
    float s = v * a_src[lane];
    float d = v * a_dst[lane];
    s += __shfl_xor(s, 1); s += __shfl_xor(s, 2); s += __shfl_xor(s, 4);
    d += __shfl_xor(d, 1); d += __shfl_xor(d, 2); d += __shfl_xor(d, 4);
    if ((lane & 7) == 0) {
        as1[node * 8 + (lane >> 3)] = s;
        ad1[node * 8 + (lane >> 3)] = d;
    }
}

// ---------------- CSR build: histogram -> scan -> scatter ----------------
__global__ __launch_bounds__(256) void k_hist(const int* __restrict__ ei, int* __restrict__ deg) {
    int e = blockIdx.x * 256 + threadIdx.x;
    if (e < N_EDGES) atomicAdd(&deg[ei[N_EDGES + e]], 1);
}

// per-block inclusive scan of deg (1024 elems/block), record block sums
__global__ __launch_bounds__(256) void k_scan_a(const int* __restrict__ deg,
                                                int* __restrict__ S,
                                                int* __restrict__ blockSum) {
    __shared__ int lds[256];
    int t = threadIdx.x;
    int base = blockIdx.x * 1024 + t * 4;
    int v[4]; int sum = 0;
    #pragma unroll
    for (int k = 0; k < 4; ++k) { int i = base + k; v[k] = (i < N_NODES) ? deg[i] : 0; sum += v[k]; }
    lds[t] = sum; __syncthreads();
    for (int off = 1; off < 256; off <<= 1) {
        int x = lds[t];
        int y = (t >= off) ? lds[t - off] : 0;
        __syncthreads();
        lds[t] = x + y;
        __syncthreads();
    }
    int prefix = lds[t] - sum;   // exclusive prefix for this thread
    int run = prefix;
    #pragma unroll
    for (int k = 0; k < 4; ++k) {
        run += v[k];
        int i = base + k;
        if (i < N_NODES) S[i] = run;   // block-local inclusive
    }
    if (t == 255) blockSum[blockIdx.x] = lds[255];
}

__global__ __launch_bounds__(256) void k_scan_b(const int* __restrict__ blockSum,
                                                int* __restrict__ blockOff) {
    __shared__ int lds[256];
    int t = threadIdx.x;
    int v = (t < NB) ? blockSum[t] : 0;
    lds[t] = v; __syncthreads();
    for (int off = 1; off < 256; off <<= 1) {
        int x = lds[t];
        int y = (t >= off) ? lds[t - off] : 0;
        __syncthreads();
        lds[t] = x + y;
        __syncthreads();
    }
    if (t < NB) blockOff[t] = lds[t] - v;   // exclusive
}

__global__ __launch_bounds__(256) void k_scan_c(int* __restrict__ S,
                                                const int* __restrict__ deg,
                                                const int* __restrict__ blockOff,
                                                int* __restrict__ cursor) {
    int i = blockIdx.x * 256 + threadIdx.x;
    if (i < N_NODES) {
        int s = S[i] + blockOff[i >> 10];
        S[i] = s;
        cursor[i] = s - deg[i];
    }
}

__global__ __launch_bounds__(256) void k_scatter(const int* __restrict__ ei,
                                                 int* __restrict__ cursor,
                                                 int* __restrict__ ssrc) {
    int e = blockIdx.x * 256 + threadIdx.x;
    if (e < N_EDGES) {
        int d = ei[N_EDGES + e];
        int pos = atomicAdd(&cursor[d], 1);
        ssrc[pos] = ei[e];
    }
}

// ---------------- layer-1 aggregate + elu + @W2 + alpha2, fused ----------------
// one 64-lane wave per node; lane = output channel; head = lane>>3
__global__ __launch_bounds__(256) void k_agg1(const int* __restrict__ ssrc,
                                              const int* __restrict__ S,
                                              const int* __restrict__ deg,
                                              const float* __restrict__ h1,
                                              const float* __restrict__ as1,
                                              const float* __restrict__ ad1,
                                              const float* __restrict__ b1,
                                              const float* __restrict__ W2,
                                              const float* __restrict__ a_src2,
                                              const float* __restrict__ a_dst2,
                                              float* __restrict__ h2,
                                              float* __restrict__ as2,
                                              float* __restrict__ ad2) {
    int node = blockIdx.x * 4 + (threadIdx.x >> 6);
    int lane = threadIdx.x & 63;
    if (node >= N_NODES) return;
    int h = lane >> 3;
    int end = S[node], start = end - deg[node];
    float adh = ad1[node * 8 + h];
    // self loop
    float ev = as1[node * 8 + h] + adh;
    ev = ev > 0.f ? ev : NEG * ev;
    float w = __expf(ev);
    float acc = w * h1[node * 64 + lane];
    float z = w;
    for (int i = start; i < end; ++i) {
        int s = ssrc[i];
        float e2 = as1[s * 8 + h] + adh;
        e2 = e2 > 0.f ? e2 : NEG * e2;
        float ww = __expf(e2);
        acc += ww * h1[s * 64 + lane];
        z += ww;
    }
    float o = acc / z + b1[lane];
    o = o > 0.f ? o : expm1f(o);
    float p0 = o * W2[lane * 2 + 0];
    float p1 = o * W2[lane * 2 + 1];
    #pragma unroll
    for (int m = 1; m < 64; m <<= 1) { p0 += __shfl_xor(p0, m); p1 += __shfl_xor(p1, m); }
    if (lane == 0) {
        h2[node * 2 + 0] = p0;
        h2[node * 2 + 1] = p1;
        as2[node] = p0 * a_src2[0] + p1 * a_src2[1];
        ad2[node] = p0 * a_dst2[0] + p1 * a_dst2[1];
    }
}

// ---------------- layer-2 aggregate + log_softmax, fused ----------------
// 16 lanes per node
__global__ __launch_bounds__(256) void k_agg2(const int* __restrict__ ssrc,
                                              const int* __restrict__ S,
                                              const int* __restrict__ deg,
                                              const float* __restrict__ h2,
                                              const float* __restrict__ as2,
                                              const float* __restrict__ ad2,
                                              const float* __restrict__ b2,
                                              float* __restrict__ out) {
    int node = blockIdx.x * 16 + (threadIdx.x >> 4);
    int j = threadIdx.x & 15;
    if (node >= N_NODES) return;
    int end = S[node], start = end - deg[node];
    float ad = ad2[node];
    float acc0 = 0.f, acc1 = 0.f, z = 0.f;
    if (j == 0) {   // self loop
        float ev = as2[node] + ad;
        ev = ev > 0.f ? ev : NEG * ev;
        float w = __expf(ev);
        acc0 = w * h2[node * 2 + 0];
        acc1 = w * h2[node * 2 + 1];
        z = w;
    }
    for (int i = start + j; i < end; i += 16) {
        int s = ssrc[i];
        float ev = as2[s] + ad;
        ev = ev > 0.f ? ev : NEG * ev;
        float w = __expf(ev);
        acc0 += w * h2[s * 2 + 0];
        acc1 += w * h2[s * 2 + 1];
        z += w;
    }
    #pragma unroll
    for (int m = 1; m < 16; m <<= 1) {
        acc0 += __shfl_xor(acc0, m);
        acc1 += __shfl_xor(acc1, m);
        z    += __shfl_xor(z, m);
    }
    if (j == 0) {
        float v0 = acc0 / z + b2[0];
        float v1 = acc1 / z + b2[1];
        float m = fmaxf(v0, v1);
        float lse = m + logf(__expf(v0 - m) + __expf(v1 - m));
        out[node * 2 + 0] = v0 - lse;
        out[node * 2 + 1] = v1 - lse;
    }
}

extern "C" void kernel_launch(void* const* d_in, const int* in_sizes, int n_in,
                              void* d_out, int out_size, void* d_ws, size_t ws_size,
                              hipStream_t stream) {
    const float* x      = (const float*)d_in[0];
    const int*   ei     = (const int*)d_in[1];
    const float* W1     = (const float*)d_in[2];
    const float* a_src1 = (const float*)d_in[3];
    const float* a_dst1 = (const float*)d_in[4];
    const float* b1     = (const float*)d_in[5];
    const float* W2     = (const float*)d_in[6];
    const float* a_src2 = (const float*)d_in[7];
    const float* a_dst2 = (const float*)d_in[8];
    const float* b2     = (const float*)d_in[9];
    float* out = (float*)d_out;

    float* p = (float*)d_ws;
    float* h1   = p; p += N_NODES * 64;
    float* as1  = p; p += N_NODES * 8;
    float* ad1  = p; p += N_NODES * 8;
    float* h2   = p; p += N_NODES * 2;
    float* as2  = p; p += N_NODES;
    float* ad2  = p; p += N_NODES;
    int* ip = (int*)p;
    int* deg      = ip; ip += N_NODES;
    int* S        = ip; ip += N_NODES;
    int* cursor   = ip; ip += N_NODES;
    int* blockSum = ip; ip += 256;
    int* blockOff = ip; ip += 256;
    int* ssrc     = ip; ip += N_EDGES;

    hipMemsetAsync(deg, 0, N_NODES * sizeof(int), stream);

    // CSR build
    k_hist<<<(N_EDGES + 255) / 256, 256, 0, stream>>>(ei, deg);
    k_scan_a<<<NB, 256, 0, stream>>>(deg, S, blockSum);
    k_scan_b<<<1, 256, 0, stream>>>(blockSum, blockOff);
    k_scan_c<<<(N_NODES + 255) / 256, 256, 0, stream>>>(S, deg, blockOff, cursor);
    k_scatter<<<(N_EDGES + 255) / 256, 256, 0, stream>>>(ei, cursor, ssrc);

    // layer 1
    k_gemm1<<<(N_NODES + 63) / 64, 256, 0, stream>>>(x, W1, h1);
    k_alpha1<<<(N_NODES + 3) / 4, 256, 0, stream>>>(h1, a_src1, a_dst1, as1, ad1);
    k_agg1<<<(N_NODES + 3) / 4, 256, 0, stream>>>(ssrc, S, deg, h1, as1, ad1, b1, W2,
                                                  a_src2, a_dst2, h2, as2, ad2);
    // layer 2 + log_softmax
    k_agg2<<<(N_NODES + 15) / 16, 256, 0, stream>>>(ssrc, S, deg, h2, as2, ad2, b2, out);
}

// Round 3
// 366.013 us; speedup vs baseline: 9.5840x; 1.4718x over previous
//
#include <hip/hip_runtime.h>
#include <math.h>

#define N_NODES 100000
#define N_EDGES 1600000
#define F_IN 165
#define NEG 0.2f
#define NB 98          // ceil(N_NODES / 1024) scan blocks

// ---------------- K1: h1 = x @ W1, fused as1/ad1 epilogue ----------------
// 64x64 tile, 256 threads, 4x4 per thread (cols tc*4..tc*4+3 -> float4 I/O).
__global__ __launch_bounds__(256) void k_gemm1(const float* __restrict__ x,
                                               const float* __restrict__ W1,
                                               const float* __restrict__ a_src1,
                                               const float* __restrict__ a_dst1,
                                               float* __restrict__ h1,
                                               float* __restrict__ as1,
                                               float* __restrict__ ad1) {
    __shared__ float Ws[32 * 64];    // 8 KB, one 32-k chunk of W1
    __shared__ float xs[64 * 34];    // 8.7 KB, 64 rows x 32 k (+2 pad)
    const int t = threadIdx.x;
    const int tr = t >> 4, tc = t & 15;
    const int base = blockIdx.x * 64;
    float acc[4][4] = {};
    for (int k0 = 0; k0 < F_IN; k0 += 32) {
        __syncthreads();
        #pragma unroll
        for (int i = t; i < 2048; i += 256) {
            int idx = k0 * 64 + i;
            Ws[i] = (idx < F_IN * 64) ? W1[idx] : 0.f;
        }
        #pragma unroll
        for (int i = t; i < 2048; i += 256) {
            int r = i >> 5, kk = i & 31;
            int row = base + r, k = k0 + kk;
            xs[r * 34 + kk] = (row < N_NODES && k < F_IN) ? x[row * F_IN + k] : 0.f;
        }
        __syncthreads();
        #pragma unroll
        for (int kk = 0; kk < 32; ++kk) {
            float4 wv = *(const float4*)&Ws[kk * 64 + tc * 4];
            #pragma unroll
            for (int i = 0; i < 4; ++i) {
                float xv = xs[(tr * 4 + i) * 34 + kk];
                acc[i][0] = fmaf(xv, wv.x, acc[i][0]);
                acc[i][1] = fmaf(xv, wv.y, acc[i][1]);
                acc[i][2] = fmaf(xv, wv.z, acc[i][2]);
                acc[i][3] = fmaf(xv, wv.w, acc[i][3]);
            }
        }
    }
    // epilogue: h1 store + fused per-head alpha reduction.
    // cols tc*4..tc*4+3 all lie in head hh = tc>>1; partner lane tc^1 has the
    // other half of the head -> one shfl_xor(1) completes the 8-wide dot.
    float4 av = ((const float4*)a_src1)[tc];
    float4 dv = ((const float4*)a_dst1)[tc];
    int hh = tc >> 1;
    #pragma unroll
    for (int i = 0; i < 4; ++i) {
        int row = base + tr * 4 + i;
        if (row < N_NODES) {
            float ps = acc[i][0] * av.x + acc[i][1] * av.y + acc[i][2] * av.z + acc[i][3] * av.w;
            float pd = acc[i][0] * dv.x + acc[i][1] * dv.y + acc[i][2] * dv.z + acc[i][3] * dv.w;
            ps += __shfl_xor(ps, 1);
            pd += __shfl_xor(pd, 1);
            *(float4*)&h1[row * 64 + tc * 4] =
                make_float4(acc[i][0], acc[i][1], acc[i][2], acc[i][3]);
            if ((tc & 1) == 0) {
                as1[row * 8 + hh] = ps;
                ad1[row * 8 + hh] = pd;
            }
        }
    }
}

// ---------------- CSR build: histogram -> scan -> scatter ----------------
__global__ __launch_bounds__(256) void k_hist(const int* __restrict__ ei, int* __restrict__ deg) {
    int e = blockIdx.x * 256 + threadIdx.x;
    if (e < N_EDGES) atomicAdd(&deg[ei[N_EDGES + e]], 1);
}

__global__ __launch_bounds__(256) void k_scan_a(const int* __restrict__ deg,
                                                int* __restrict__ S,
                                                int* __restrict__ blockSum) {
    __shared__ int lds[256];
    int t = threadIdx.x;
    int base = blockIdx.x * 1024 + t * 4;
    int v[4]; int sum = 0;
    #pragma unroll
    for (int k = 0; k < 4; ++k) { int i = base + k; v[k] = (i < N_NODES) ? deg[i] : 0; sum += v[k]; }
    lds[t] = sum; __syncthreads();
    for (int off = 1; off < 256; off <<= 1) {
        int x = lds[t];
        int y = (t >= off) ? lds[t - off] : 0;
        __syncthreads();
        lds[t] = x + y;
        __syncthreads();
    }
    int prefix = lds[t] - sum;
    int run = prefix;
    #pragma unroll
    for (int k = 0; k < 4; ++k) {
        run += v[k];
        int i = base + k;
        if (i < N_NODES) S[i] = run;
    }
    if (t == 255) blockSum[blockIdx.x] = lds[255];
}

__global__ __launch_bounds__(256) void k_scan_b(const int* __restrict__ blockSum,
                                                int* __restrict__ blockOff) {
    __shared__ int lds[256];
    int t = threadIdx.x;
    int v = (t < NB) ? blockSum[t] : 0;
    lds[t] = v; __syncthreads();
    for (int off = 1; off < 256; off <<= 1) {
        int x = lds[t];
        int y = (t >= off) ? lds[t - off] : 0;
        __syncthreads();
        lds[t] = x + y;
        __syncthreads();
    }
    if (t < NB) blockOff[t] = lds[t] - v;
}

__global__ __launch_bounds__(256) void k_scan_c(int* __restrict__ S,
                                                const int* __restrict__ deg,
                                                const int* __restrict__ blockOff,
                                                int* __restrict__ cursor) {
    int i = blockIdx.x * 256 + threadIdx.x;
    if (i < N_NODES) {
        int s = S[i] + blockOff[i >> 10];
        S[i] = s;
        cursor[i] = s - deg[i];
    }
}

__global__ __launch_bounds__(256) void k_scatter(const int* __restrict__ ei,
                                                 int* __restrict__ cursor,
                                                 int* __restrict__ ssrc) {
    int e = blockIdx.x * 256 + threadIdx.x;
    if (e < N_EDGES) {
        int d = ei[N_EDGES + e];
        int pos = atomicAdd(&cursor[d], 1);
        ssrc[pos] = ei[e];
    }
}

// ---------------- layer-1 aggregate + elu + @W2 + alpha2, fused ----------------
// one 64-lane wave per node; lane = channel. Edge ids loaded coalesced 64 at a
// time, broadcast via shfl; inner loop unrolled x4 for memory-level parallelism.
__global__ __launch_bounds__(256) void k_agg1(const int* __restrict__ ssrc,
                                              const int* __restrict__ S,
                                              const int* __restrict__ deg,
                                              const float* __restrict__ h1,
                                              const float* __restrict__ as1,
                                              const float* __restrict__ ad1,
                                              const float* __restrict__ b1,
                                              const float* __restrict__ W2,
                                              const float* __restrict__ a_src2,
                                              const float* __restrict__ a_dst2,
                                              float4* __restrict__ pk2) {
    int node = blockIdx.x * 4 + (threadIdx.x >> 6);
    int lane = threadIdx.x & 63;
    if (node >= N_NODES) return;
    int h = lane >> 3;
    int end = S[node], start = end - deg[node];
    float adh = ad1[node * 8 + h];
    // self loop
    float ev = as1[node * 8 + h] + adh;
    ev = fmaxf(ev, NEG * ev);
    float w = __expf(ev);
    float acc = w * h1[node * 64 + lane];
    float z = w;

    for (int c = start; c < end; c += 64) {
        int cnt = end - c; if (cnt > 64) cnt = 64;
        int sidx = (lane < cnt) ? ssrc[c + lane] : 0;
        int k = 0;
        for (; k + 4 <= cnt; k += 4) {
            int s0 = __shfl(sidx, k);
            int s1 = __shfl(sidx, k + 1);
            int s2 = __shfl(sidx, k + 2);
            int s3 = __shfl(sidx, k + 3);
            float a0 = as1[s0 * 8 + h];
            float a1 = as1[s1 * 8 + h];
            float a2 = as1[s2 * 8 + h];
            float a3 = as1[s3 * 8 + h];
            float g0 = h1[s0 * 64 + lane];
            float g1 = h1[s1 * 64 + lane];
            float g2 = h1[s2 * 64 + lane];
            float g3 = h1[s3 * 64 + lane];
            float e0 = a0 + adh; e0 = fmaxf(e0, NEG * e0); float w0 = __expf(e0);
            float e1 = a1 + adh; e1 = fmaxf(e1, NEG * e1); float w1 = __expf(e1);
            float e2 = a2 + adh; e2 = fmaxf(e2, NEG * e2); float w2 = __expf(e2);
            float e3 = a3 + adh; e3 = fmaxf(e3, NEG * e3); float w3 = __expf(e3);
            acc = fmaf(w0, g0, acc); acc = fmaf(w1, g1, acc);
            acc = fmaf(w2, g2, acc); acc = fmaf(w3, g3, acc);
            z += (w0 + w1) + (w2 + w3);
        }
        for (; k < cnt; ++k) {
            int s = __shfl(sidx, k);
            float a = as1[s * 8 + h];
            float g = h1[s * 64 + lane];
            float e2 = a + adh; e2 = fmaxf(e2, NEG * e2);
            float ww = __expf(e2);
            acc = fmaf(ww, g, acc);
            z += ww;
        }
    }

    float o = acc / z + b1[lane];
    o = o > 0.f ? o : expm1f(o);
    float p0 = o * W2[lane * 2 + 0];
    float p1 = o * W2[lane * 2 + 1];
    #pragma unroll
    for (int m = 1; m < 64; m <<= 1) { p0 += __shfl_xor(p0, m); p1 += __shfl_xor(p1, m); }
    if (lane == 0) {
        pk2[node] = make_float4(p0, p1,
                                p0 * a_src2[0] + p1 * a_src2[1],
                                p0 * a_dst2[0] + p1 * a_dst2[1]);
    }
}

// ---------------- layer-2 aggregate + log_softmax, fused ----------------
// 16 lanes per node; one float4 gather per edge; unroll x2.
__global__ __launch_bounds__(256) void k_agg2(const int* __restrict__ ssrc,
                                              const int* __restrict__ S,
                                              const int* __restrict__ deg,
                                              const float4* __restrict__ pk2,
                                              const float* __restrict__ b2,
                                              float* __restrict__ out) {
    int node = blockIdx.x * 16 + (threadIdx.x >> 4);
    int j = threadIdx.x & 15;
    if (node >= N_NODES) return;
    int end = S[node], start = end - deg[node];
    float4 self = pk2[node];
    float ad = self.w;
    float acc0 = 0.f, acc1 = 0.f, z = 0.f;
    if (j == 0) {
        float ev = self.z + ad;
        ev = fmaxf(ev, NEG * ev);
        float w = __expf(ev);
        acc0 = w * self.x; acc1 = w * self.y; z = w;
    }
    int i = start + j;
    for (; i + 16 < end; i += 32) {
        int s0 = ssrc[i], s1 = ssrc[i + 16];
        float4 q0 = pk2[s0], q1 = pk2[s1];
        float e0 = q0.z + ad; e0 = fmaxf(e0, NEG * e0); float w0 = __expf(e0);
        float e1 = q1.z + ad; e1 = fmaxf(e1, NEG * e1); float w1 = __expf(e1);
        acc0 = fmaf(w0, q0.x, acc0); acc0 = fmaf(w1, q1.x, acc0);
        acc1 = fmaf(w0, q0.y, acc1); acc1 = fmaf(w1, q1.y, acc1);
        z += w0 + w1;
    }
    if (i < end) {
        int s = ssrc[i];
        float4 q = pk2[s];
        float e0 = q.z + ad; e0 = fmaxf(e0, NEG * e0); float w0 = __expf(e0);
        acc0 = fmaf(w0, q.x, acc0);
        acc1 = fmaf(w0, q.y, acc1);
        z += w0;
    }
    #pragma unroll
    for (int m = 1; m < 16; m <<= 1) {
        acc0 += __shfl_xor(acc0, m);
        acc1 += __shfl_xor(acc1, m);
        z    += __shfl_xor(z, m);
    }
    if (j == 0) {
        float v0 = acc0 / z + b2[0];
        float v1 = acc1 / z + b2[1];
        float m = fmaxf(v0, v1);
        float lse = m + logf(__expf(v0 - m) + __expf(v1 - m));
        out[node * 2 + 0] = v0 - lse;
        out[node * 2 + 1] = v1 - lse;
    }
}

extern "C" void kernel_launch(void* const* d_in, const int* in_sizes, int n_in,
                              void* d_out, int out_size, void* d_ws, size_t ws_size,
                              hipStream_t stream) {
    const float* x      = (const float*)d_in[0];
    const int*   ei     = (const int*)d_in[1];
    const float* W1     = (const float*)d_in[2];
    const float* a_src1 = (const float*)d_in[3];
    const float* a_dst1 = (const float*)d_in[4];
    const float* b1     = (const float*)d_in[5];
    const float* W2     = (const float*)d_in[6];
    const float* a_src2 = (const float*)d_in[7];
    const float* a_dst2 = (const float*)d_in[8];
    const float* b2     = (const float*)d_in[9];
    float* out = (float*)d_out;

    float* p = (float*)d_ws;
    float* h1   = p; p += N_NODES * 64;
    float* as1  = p; p += N_NODES * 8;
    float* ad1  = p; p += N_NODES * 8;
    float4* pk2 = (float4*)p; p += N_NODES * 4;
    int* ip = (int*)p;
    int* deg      = ip; ip += N_NODES;
    int* S        = ip; ip += N_NODES;
    int* cursor   = ip; ip += N_NODES;
    int* blockSum = ip; ip += 256;
    int* blockOff = ip; ip += 256;
    int* ssrc     = ip; ip += N_EDGES;

    hipMemsetAsync(deg, 0, N_NODES * sizeof(int), stream);

    // CSR build
    k_hist<<<(N_EDGES + 255) / 256, 256, 0, stream>>>(ei, deg);
    k_scan_a<<<NB, 256, 0, stream>>>(deg, S, blockSum);
    k_scan_b<<<1, 256, 0, stream>>>(blockSum, blockOff);
    k_scan_c<<<(N_NODES + 255) / 256, 256, 0, stream>>>(S, deg, blockOff, cursor);
    k_scatter<<<(N_EDGES + 255) / 256, 256, 0, stream>>>(ei, cursor, ssrc);

    // layer 1 (gemm fused with alpha)
    k_gemm1<<<(N_NODES + 63) / 64, 256, 0, stream>>>(x, W1, a_src1, a_dst1, h1, as1, ad1);
    k_agg1<<<(N_NODES + 3) / 4, 256, 0, stream>>>(ssrc, S, deg, h1, as1, ad1, b1, W2,
                                                  a_src2, a_dst2, pk2);
    // layer 2 + log_softmax
    k_agg2<<<(N_NODES + 15) / 16, 256, 0, stream>>>(ssrc, S, deg, pk2, b2, out);
}

// Round 4
// 317.975 us; speedup vs baseline: 11.0320x; 1.1511x over previous
//
#include <hip/hip_runtime.h>
#include <math.h>

#define N_NODES 100000
#define N_EDGES 1600000
#define F_IN 165
#define NEG 0.2f
#define NB 98            // ceil(N_NODES / 1024) scan blocks
#define NXCD 8
#define RSZ 12500        // N_NODES / NXCD, exact
#define EPB 1024         // edges per block-chunk (256 thr x 4)
#define NCHUNK ((N_EDGES + EPB - 1) / EPB)

// ---------------- K1: h1 = x @ W1, fused as1/ad1 epilogue ----------------
__global__ __launch_bounds__(256) void k_gemm1(const float* __restrict__ x,
                                               const float* __restrict__ W1,
                                               const float* __restrict__ a_src1,
                                               const float* __restrict__ a_dst1,
                                               float* __restrict__ h1,
                                               float* __restrict__ as1,
                                               float* __restrict__ ad1) {
    __shared__ float Ws[32 * 64];
    __shared__ float xs[64 * 34];
    const int t = threadIdx.x;
    const int tr = t >> 4, tc = t & 15;
    const int base = blockIdx.x * 64;
    float acc[4][4] = {};
    for (int k0 = 0; k0 < F_IN; k0 += 32) {
        __syncthreads();
        #pragma unroll
        for (int i = t; i < 2048; i += 256) {
            int idx = k0 * 64 + i;
            Ws[i] = (idx < F_IN * 64) ? W1[idx] : 0.f;
        }
        #pragma unroll
        for (int i = t; i < 2048; i += 256) {
            int r = i >> 5, kk = i & 31;
            int row = base + r, k = k0 + kk;
            xs[r * 34 + kk] = (row < N_NODES && k < F_IN) ? x[row * F_IN + k] : 0.f;
        }
        __syncthreads();
        #pragma unroll
        for (int kk = 0; kk < 32; ++kk) {
            float4 wv = *(const float4*)&Ws[kk * 64 + tc * 4];
            #pragma unroll
            for (int i = 0; i < 4; ++i) {
                float xv = xs[(tr * 4 + i) * 34 + kk];
                acc[i][0] = fmaf(xv, wv.x, acc[i][0]);
                acc[i][1] = fmaf(xv, wv.y, acc[i][1]);
                acc[i][2] = fmaf(xv, wv.z, acc[i][2]);
                acc[i][3] = fmaf(xv, wv.w, acc[i][3]);
            }
        }
    }
    float4 av = ((const float4*)a_src1)[tc];
    float4 dv = ((const float4*)a_dst1)[tc];
    int hh = tc >> 1;
    #pragma unroll
    for (int i = 0; i < 4; ++i) {
        int row = base + tr * 4 + i;
        if (row < N_NODES) {
            float ps = acc[i][0] * av.x + acc[i][1] * av.y + acc[i][2] * av.z + acc[i][3] * av.w;
            float pd = acc[i][0] * dv.x + acc[i][1] * dv.y + acc[i][2] * dv.z + acc[i][3] * dv.w;
            ps += __shfl_xor(ps, 1);
            pd += __shfl_xor(pd, 1);
            *(float4*)&h1[row * 64 + tc * 4] =
                make_float4(acc[i][0], acc[i][1], acc[i][2], acc[i][3]);
            if ((tc & 1) == 0) {
                as1[row * 8 + hh] = ps;
                ad1[row * 8 + hh] = pd;
            }
        }
    }
}

// ---------------- CSR build, XCD-range-partitioned ----------------
// blockIdx % 8 -> XCD (round-robin dispatch); each XCD owns dst range
// [r*RSZ, (r+1)*RSZ): its deg atomics and ssrc writes stay in ONE L2.
__global__ __launch_bounds__(256) void k_hist(const int* __restrict__ ei,
                                              int* __restrict__ deg) {
    int r = blockIdx.x & (NXCD - 1);
    int chunk = blockIdx.x >> 3;
    int lo = r * RSZ;
    long e0 = (long)chunk * EPB + threadIdx.x * 4;
    if (e0 >= N_EDGES) return;
    int4 d4 = *(const int4*)(ei + N_EDGES + e0);   // N_EDGES%4==0, e0%4==0
    #pragma unroll
    for (int k = 0; k < 4; ++k) {
        int d = (&d4.x)[k];
        if ((unsigned)(d - lo) < RSZ) atomicAdd(&deg[d], 1);
    }
}

__global__ __launch_bounds__(256) void k_scan_a(const int* __restrict__ deg,
                                                int* __restrict__ S,
                                                int* __restrict__ blockSum) {
    __shared__ int lds[256];
    int t = threadIdx.x;
    int base = blockIdx.x * 1024 + t * 4;
    int v[4]; int sum = 0;
    #pragma unroll
    for (int k = 0; k < 4; ++k) { int i = base + k; v[k] = (i < N_NODES) ? deg[i] : 0; sum += v[k]; }
    lds[t] = sum; __syncthreads();
    for (int off = 1; off < 256; off <<= 1) {
        int x = lds[t];
        int y = (t >= off) ? lds[t - off] : 0;
        __syncthreads();
        lds[t] = x + y;
        __syncthreads();
    }
    int run = lds[t] - sum;
    #pragma unroll
    for (int k = 0; k < 4; ++k) {
        run += v[k];
        int i = base + k;
        if (i < N_NODES) S[i] = run;
    }
    if (t == 255) blockSum[blockIdx.x] = lds[255];
}

__global__ __launch_bounds__(256) void k_scan_b(const int* __restrict__ blockSum,
                                                int* __restrict__ blockOff) {
    __shared__ int lds[256];
    int t = threadIdx.x;
    int v = (t < NB) ? blockSum[t] : 0;
    lds[t] = v; __syncthreads();
    for (int off = 1; off < 256; off <<= 1) {
        int x = lds[t];
        int y = (t >= off) ? lds[t - off] : 0;
        __syncthreads();
        lds[t] = x + y;
        __syncthreads();
    }
    if (t < NB) blockOff[t] = lds[t] - v;
}

__global__ __launch_bounds__(256) void k_scan_c(int* __restrict__ S,
                                                const int* __restrict__ deg,
                                                const int* __restrict__ blockOff,
                                                int* __restrict__ cursor) {
    int i = blockIdx.x * 256 + threadIdx.x;
    if (i < N_NODES) {
        int s = S[i] + blockOff[i >> 10];
        S[i] = s;
        cursor[i] = s - deg[i];
    }
}

__global__ __launch_bounds__(256) void k_scatter(const int* __restrict__ ei,
                                                 int* __restrict__ cursor,
                                                 int* __restrict__ ssrc) {
    int r = blockIdx.x & (NXCD - 1);
    int chunk = blockIdx.x >> 3;
    int lo = r * RSZ;
    long e0 = (long)chunk * EPB + threadIdx.x * 4;
    if (e0 >= N_EDGES) return;
    int4 s4 = *(const int4*)(ei + e0);
    int4 d4 = *(const int4*)(ei + N_EDGES + e0);
    #pragma unroll
    for (int k = 0; k < 4; ++k) {
        int d = (&d4.x)[k];
        if ((unsigned)(d - lo) < RSZ) {
            int pos = atomicAdd(&cursor[d], 1);
            ssrc[pos] = (&s4.x)[k];   // pos lies in this XCD's contiguous region
        }
    }
}

// ---------------- layer-1 aggregate + elu + @W2 + alpha2, fused ----------------
__global__ __launch_bounds__(256) void k_agg1(const int* __restrict__ ssrc,
                                              const int* __restrict__ S,
                                              const int* __restrict__ deg,
                                              const float* __restrict__ h1,
                                              const float* __restrict__ as1,
                                              const float* __restrict__ ad1,
                                              const float* __restrict__ b1,
                                              const float* __restrict__ W2,
                                              const float* __restrict__ a_src2,
                                              const float* __restrict__ a_dst2,
                                              float4* __restrict__ pk2) {
    int node = blockIdx.x * 4 + (threadIdx.x >> 6);
    int lane = threadIdx.x & 63;
    if (node >= N_NODES) return;
    int h = lane >> 3;
    int end = S[node], start = end - deg[node];
    float adh = ad1[node * 8 + h];
    float ev = as1[node * 8 + h] + adh;
    ev = fmaxf(ev, NEG * ev);
    float w = __expf(ev);
    float acc = w * h1[node * 64 + lane];
    float z = w;

    for (int c = start; c < end; c += 64) {
        int cnt = end - c; if (cnt > 64) cnt = 64;
        int sidx = (lane < cnt) ? ssrc[c + lane] : 0;
        int k = 0;
        for (; k + 4 <= cnt; k += 4) {
            int s0 = __shfl(sidx, k);
            int s1 = __shfl(sidx, k + 1);
            int s2 = __shfl(sidx, k + 2);
            int s3 = __shfl(sidx, k + 3);
            float a0 = as1[s0 * 8 + h];
            float a1 = as1[s1 * 8 + h];
            float a2 = as1[s2 * 8 + h];
            float a3 = as1[s3 * 8 + h];
            float g0 = h1[s0 * 64 + lane];
            float g1 = h1[s1 * 64 + lane];
            float g2 = h1[s2 * 64 + lane];
            float g3 = h1[s3 * 64 + lane];
            float e0 = a0 + adh; e0 = fmaxf(e0, NEG * e0); float w0 = __expf(e0);
            float e1 = a1 + adh; e1 = fmaxf(e1, NEG * e1); float w1 = __expf(e1);
            float e2 = a2 + adh; e2 = fmaxf(e2, NEG * e2); float w2 = __expf(e2);
            float e3 = a3 + adh; e3 = fmaxf(e3, NEG * e3); float w3 = __expf(e3);
            acc = fmaf(w0, g0, acc); acc = fmaf(w1, g1, acc);
            acc = fmaf(w2, g2, acc); acc = fmaf(w3, g3, acc);
            z += (w0 + w1) + (w2 + w3);
        }
        for (; k < cnt; ++k) {
            int s = __shfl(sidx, k);
            float a = as1[s * 8 + h];
            float g = h1[s * 64 + lane];
            float e2 = a + adh; e2 = fmaxf(e2, NEG * e2);
            float ww = __expf(e2);
            acc = fmaf(ww, g, acc);
            z += ww;
        }
    }

    float o = acc / z + b1[lane];
    o = o > 0.f ? o : expm1f(o);
    float p0 = o * W2[lane * 2 + 0];
    float p1 = o * W2[lane * 2 + 1];
    #pragma unroll
    for (int m = 1; m < 64; m <<= 1) { p0 += __shfl_xor(p0, m); p1 += __shfl_xor(p1, m); }
    if (lane == 0) {
        pk2[node] = make_float4(p0, p1,
                                p0 * a_src2[0] + p1 * a_src2[1],
                                p0 * a_dst2[0] + p1 * a_dst2[1]);
    }
}

// ---------------- layer-2 aggregate + log_softmax, fused ----------------
__global__ __launch_bounds__(256) void k_agg2(const int* __restrict__ ssrc,
                                              const int* __restrict__ S,
                                              const int* __restrict__ deg,
                                              const float4* __restrict__ pk2,
                                              const float* __restrict__ b2,
                                              float* __restrict__ out) {
    int node = blockIdx.x * 16 + (threadIdx.x >> 4);
    int j = threadIdx.x & 15;
    if (node >= N_NODES) return;
    int end = S[node], start = end - deg[node];
    float4 self = pk2[node];
    float ad = self.w;
    float acc0 = 0.f, acc1 = 0.f, z = 0.f;
    if (j == 0) {
        float ev = self.z + ad;
        ev = fmaxf(ev, NEG * ev);
        float w = __expf(ev);
        acc0 = w * self.x; acc1 = w * self.y; z = w;
    }
    int i = start + j;
    for (; i + 16 < end; i += 32) {
        int s0 = ssrc[i], s1 = ssrc[i + 16];
        float4 q0 = pk2[s0], q1 = pk2[s1];
        float e0 = q0.z + ad; e0 = fmaxf(e0, NEG * e0); float w0 = __expf(e0);
        float e1 = q1.z + ad; e1 = fmaxf(e1, NEG * e1); float w1 = __expf(e1);
        acc0 = fmaf(w0, q0.x, acc0); acc0 = fmaf(w1, q1.x, acc0);
        acc1 = fmaf(w0, q0.y, acc1); acc1 = fmaf(w1, q1.y, acc1);
        z += w0 + w1;
    }
    if (i < end) {
        int s = ssrc[i];
        float4 q = pk2[s];
        float e0 = q.z + ad; e0 = fmaxf(e0, NEG * e0); float w0 = __expf(e0);
        acc0 = fmaf(w0, q.x, acc0);
        acc1 = fmaf(w0, q.y, acc1);
        z += w0;
    }
    #pragma unroll
    for (int m = 1; m < 16; m <<= 1) {
        acc0 += __shfl_xor(acc0, m);
        acc1 += __shfl_xor(acc1, m);
        z    += __shfl_xor(z, m);
    }
    if (j == 0) {
        float v0 = acc0 / z + b2[0];
        float v1 = acc1 / z + b2[1];
        float m = fmaxf(v0, v1);
        float lse = m + logf(__expf(v0 - m) + __expf(v1 - m));
        out[node * 2 + 0] = v0 - lse;
        out[node * 2 + 1] = v1 - lse;
    }
}

extern "C" void kernel_launch(void* const* d_in, const int* in_sizes, int n_in,
                              void* d_out, int out_size, void* d_ws, size_t ws_size,
                              hipStream_t stream) {
    const float* x      = (const float*)d_in[0];
    const int*   ei     = (const int*)d_in[1];
    const float* W1     = (const float*)d_in[2];
    const float* a_src1 = (const float*)d_in[3];
    const float* a_dst1 = (const float*)d_in[4];
    const float* b1     = (const float*)d_in[5];
    const float* W2     = (const float*)d_in[6];
    const float* a_src2 = (const float*)d_in[7];
    const float* a_dst2 = (const float*)d_in[8];
    const float* b2     = (const float*)d_in[9];
    float* out = (float*)d_out;

    float* p = (float*)d_ws;
    float* h1   = p; p += N_NODES * 64;
    float* as1  = p; p += N_NODES * 8;
    float* ad1  = p; p += N_NODES * 8;
    float4* pk2 = (float4*)p; p += N_NODES * 4;
    int* ip = (int*)p;
    int* deg      = ip; ip += N_NODES;
    int* S        = ip; ip += N_NODES;
    int* cursor   = ip; ip += N_NODES;
    int* blockSum = ip; ip += 256;
    int* blockOff = ip; ip += 256;
    int* ssrc     = ip; ip += N_EDGES;

    hipMemsetAsync(deg, 0, N_NODES * sizeof(int), stream);

    // CSR build (XCD-range-partitioned hist & scatter)
    k_hist<<<NCHUNK * NXCD, 256, 0, stream>>>(ei, deg);
    k_scan_a<<<NB, 256, 0, stream>>>(deg, S, blockSum);
    k_scan_b<<<1, 256, 0, stream>>>(blockSum, blockOff);
    k_scan_c<<<(N_NODES + 255) / 256, 256, 0, stream>>>(S, deg, blockOff, cursor);
    k_scatter<<<NCHUNK * NXCD, 256, 0, stream>>>(ei, cursor, ssrc);

    // layer 1 (gemm fused with alpha)
    k_gemm1<<<(N_NODES + 63) / 64, 256, 0, stream>>>(x, W1, a_src1, a_dst1, h1, as1, ad1);
    k_agg1<<<(N_NODES + 3) / 4, 256, 0, stream>>>(ssrc, S, deg, h1, as1, ad1, b1, W2,
                                                  a_src2, a_dst2, pk2);
    // layer 2 + log_softmax
    k_agg2<<<(N_NODES + 15) / 16, 256, 0, stream>>>(ssrc, S, deg, pk2, b2, out);
}